// Round 1
// baseline (260.650 us; speedup 1.0000x reference)
//
#include <hip/hip_runtime.h>
#include <stdint.h>

// ---------------------------------------------------------------------------
// Fused attention: out = dropout(softmax(0.5 * x1 @ x2^T), p=0.2, jax key 42) @ x2
// B=8, M=N=2048, D=128, fp32 in/out. bf16 MFMA (16x16x32), flash-style online
// softmax, bitwise-exact JAX threefry dropout mask.
// ---------------------------------------------------------------------------

#define JAX_PARTITIONABLE 1   // 1: jax>=0.5 default (counter=(0,i), bits=o0^o1)
                              // 0: legacy iota-split scheme

typedef __bf16 bf16x8 __attribute__((ext_vector_type(8)));
typedef float f32x4 __attribute__((ext_vector_type(4)));

union FragAB {
  bf16x8 v;
  uint32_t u[4];
};

__device__ __forceinline__ uint32_t rotl32(uint32_t x, uint32_t r) {
  return (x << r) | (x >> (32u - r));   // -> v_alignbit_b32
}

// JAX threefry2x32 with key (0, 42) (jax.random.key(42) -> (hi=0, lo=42))
__device__ __forceinline__ void threefry2x32_k42(uint32_t in0, uint32_t in1,
                                                 uint32_t& o0, uint32_t& o1) {
  const uint32_t ks0 = 0u;
  const uint32_t ks1 = 42u;
  const uint32_t ks2 = 0x1BD11BDAu ^ 0u ^ 42u;
  uint32_t x0 = in0 + ks0;
  uint32_t x1 = in1 + ks1;
#define TFR(r) { x0 += x1; x1 = rotl32(x1, r); x1 ^= x0; }
  TFR(13u) TFR(15u) TFR(26u) TFR(6u)
  x0 += ks1; x1 += ks2 + 1u;
  TFR(17u) TFR(29u) TFR(16u) TFR(24u)
  x0 += ks2; x1 += ks0 + 2u;
  TFR(13u) TFR(15u) TFR(26u) TFR(6u)
  x0 += ks0; x1 += ks1 + 3u;
  TFR(17u) TFR(29u) TFR(16u) TFR(24u)
  x0 += ks1; x1 += ks2 + 4u;
  TFR(13u) TFR(15u) TFR(26u) TFR(6u)
  x0 += ks2; x1 += ks0 + 5u;
#undef TFR
  o0 = x0; o1 = x1;
}

__device__ __forceinline__ uint32_t pack_bf16(float a, float b) {
  __bf16 ba = (__bf16)a;   // RTNE
  __bf16 bb = (__bf16)b;
  uint32_t ua = (uint32_t)__builtin_bit_cast(uint16_t, ba);
  uint32_t ub = (uint32_t)__builtin_bit_cast(uint16_t, bb);
  return ua | (ub << 16);
}

// keep iff uniform < 0.8f  <=>  (bits>>9) <= 6710886  <=>  bits < 6710887<<9
#define KEEP_LT 3435974144u
#define HHALF 16777216u   // legacy scheme: half of 8*2048*2048

__launch_bounds__(256, 1)
__global__ void attn_kernel(const float* __restrict__ x1,
                            const float* __restrict__ x2,
                            float* __restrict__ out) {
  constexpr int LDK = 136;  // Kt row stride (bf16 elems): 272 B, 16B-aligned, 2-way banks
  constexpr int LDV = 68;   // Vt2 row stride (uint32):    272 B, conflict-free b128 reads
  constexpr int LDP = 72;   // Pbuf row stride (bf16):     144 B, 16B-aligned, 2-way banks

  __shared__ __attribute__((aligned(16))) uint16_t Kt[64 * LDK];    // K tile row-major bf16
  __shared__ __attribute__((aligned(16))) uint32_t Vt2[64 * LDV];   // V^T tile, d-pairs packed
  __shared__ __attribute__((aligned(16))) uint16_t Pbuf[4 * 16 * LDP];

  const int tid = threadIdx.x;
  const int wave = tid >> 6;
  const int lane = tid & 63;
  const int l15 = lane & 15;
  const int g = lane >> 4;
  const int b = blockIdx.y;
  const int m0 = blockIdx.x * 64;

  // ---- Q fragments, scaled by 0.5*log2(e) so scores are in log2 domain ----
  const float QSCALE = 0.5f * 1.44269504088896340736f;
  const int m_arow = m0 + wave * 16 + l15;       // A-operand row for this lane
  FragAB qf[4];
  const float* qp_base = x1 + ((size_t)b * 2048 + m_arow) * 128;
  #pragma unroll
  for (int c = 0; c < 4; ++c) {
    const float* qp = qp_base + c * 32 + g * 8;
    float4 f0 = *(const float4*)(qp);
    float4 f1 = *(const float4*)(qp + 4);
    qf[c].u[0] = pack_bf16(f0.x * QSCALE, f0.y * QSCALE);
    qf[c].u[1] = pack_bf16(f0.z * QSCALE, f0.w * QSCALE);
    qf[c].u[2] = pack_bf16(f1.x * QSCALE, f1.y * QSCALE);
    qf[c].u[3] = pack_bf16(f1.z * QSCALE, f1.w * QSCALE);
  }

  // softmax state: this lane owns rows m0 + wave*16 + 4*g + r (C/D layout rows)
  float m2[4], lsum[4];
  #pragma unroll
  for (int r = 0; r < 4; ++r) { m2[r] = -INFINITY; lsum[r] = 0.0f; }
  f32x4 o[8];
  #pragma unroll
  for (int dt = 0; dt < 8; ++dt) o[dt] = (f32x4){0.f, 0.f, 0.f, 0.f};

  uint32_t rng_row_base[4];
  #pragma unroll
  for (int r = 0; r < 4; ++r)
    rng_row_base[r] = (uint32_t)b * 4194304u +
                      (uint32_t)(m0 + wave * 16 + 4 * g + r) * 2048u + (uint32_t)l15;
#if !JAX_PARTITIONABLE
  const bool bLow = (b < 4);
#endif

  const float* x2b = x2 + (size_t)b * 2048 * 128;

  for (int nt = 0; nt < 32; ++nt) {
    const int n0 = nt * 64;
    __syncthreads();  // previous tile's LDS reads complete before overwrite
    // ---- stage x2 rows n0..n0+63 into Kt (row-major) and Vt2 (transposed, packed) ----
    #pragma unroll
    for (int i = 0; i < 8; ++i) {
      int f = i * 256 + tid;      // float4 index in tile (64 rows x 32 quads)
      int n = f >> 5;
      int dq = f & 31;
      float4 v = *((const float4*)x2b + (size_t)(n0 + n) * 32 + dq);
      uint32_t p0 = pack_bf16(v.x, v.y);
      uint32_t p1 = pack_bf16(v.z, v.w);
      *(uint2*)&Kt[n * LDK + dq * 4] = make_uint2(p0, p1);   // 8B aligned
      Vt2[(dq * 2 + 0) * LDV + n] = p0;   // d-pair (4dq, 4dq+1) at col n
      Vt2[(dq * 2 + 1) * LDV + n] = p1;   // d-pair (4dq+2, 4dq+3)
    }
    __syncthreads();

    // ---- S = Q K^T : 4 tiles of 16 cols, K=128 over 4 chunks ----
    f32x4 s[4];
    #pragma unroll
    for (int t = 0; t < 4; ++t) {
      f32x4 acc = (f32x4){0.f, 0.f, 0.f, 0.f};
      #pragma unroll
      for (int c = 0; c < 4; ++c) {
        FragAB kb;
        uint4 kk = *(const uint4*)&Kt[(t * 16 + l15) * LDK + c * 32 + g * 8];
        kb.u[0] = kk.x; kb.u[1] = kk.y; kb.u[2] = kk.z; kb.u[3] = kk.w;
        acc = __builtin_amdgcn_mfma_f32_16x16x32_bf16(qf[c].v, kb.v, acc, 0, 0, 0);
      }
      s[t] = acc;
    }

    // ---- online softmax (log2 domain) ----
    float tmax[4];
    #pragma unroll
    for (int r = 0; r < 4; ++r)
      tmax[r] = fmaxf(fmaxf(s[0][r], s[1][r]), fmaxf(s[2][r], s[3][r]));
    #pragma unroll
    for (int off = 1; off < 16; off <<= 1) {
      #pragma unroll
      for (int r = 0; r < 4; ++r)
        tmax[r] = fmaxf(tmax[r], __shfl_xor(tmax[r], off));
    }
    float alpha[4];
    #pragma unroll
    for (int r = 0; r < 4; ++r) {
      float mn = fmaxf(m2[r], tmax[r]);
      alpha[r] = __builtin_amdgcn_exp2f(m2[r] - mn);
      m2[r] = mn;
    }
    float pvals[4][4];
    float rsum[4] = {0.f, 0.f, 0.f, 0.f};
    #pragma unroll
    for (int t = 0; t < 4; ++t) {
      #pragma unroll
      for (int r = 0; r < 4; ++r) {
        float p = __builtin_amdgcn_exp2f(s[t][r] - m2[r]);
        pvals[t][r] = p;
        rsum[r] += p;   // denominator uses UNMASKED probs
      }
    }
    #pragma unroll
    for (int off = 1; off < 16; off <<= 1) {
      #pragma unroll
      for (int r = 0; r < 4; ++r)
        rsum[r] += __shfl_xor(rsum[r], off);
    }
    #pragma unroll
    for (int r = 0; r < 4; ++r)
      lsum[r] = lsum[r] * alpha[r] + rsum[r];
    #pragma unroll
    for (int dt = 0; dt < 8; ++dt) {
      #pragma unroll
      for (int r = 0; r < 4; ++r)
        o[dt][r] *= alpha[r];
    }

    // ---- dropout mask (bitwise JAX threefry) + P -> LDS (C/D -> A layout) ----
    uint16_t* pb = &Pbuf[wave * 16 * LDP];
    #pragma unroll
    for (int r = 0; r < 4; ++r) {
      uint32_t ibase = rng_row_base[r] + (uint32_t)n0;
      #pragma unroll
      for (int t = 0; t < 4; ++t) {
        uint32_t idx = ibase + t * 16;
        uint32_t o0, o1, bits;
#if JAX_PARTITIONABLE
        threefry2x32_k42(0u, idx, o0, o1);
        bits = o0 ^ o1;
#else
        uint32_t xa = bLow ? idx : idx - HHALF;
        uint32_t xb = bLow ? idx + HHALF : idx;
        threefry2x32_k42(xa, xb, o0, o1);
        bits = bLow ? o0 : o1;
#endif
        float pm = (bits < KEEP_LT) ? pvals[t][r] : 0.0f;
        __bf16 pmb = (__bf16)pm;
        pb[(4 * g + r) * LDP + t * 16 + l15] = __builtin_bit_cast(uint16_t, pmb);
      }
    }

    // ---- O += P V  (A-frag from Pbuf, B-frag from packed Vt2 via v_perm) ----
    const uint32_t permsel = (l15 & 1) ? 0x07060302u : 0x05040100u;
    #pragma unroll
    for (int c = 0; c < 2; ++c) {
      FragAB pa;
      uint4 pu = *(const uint4*)&pb[l15 * LDP + c * 32 + g * 8];
      pa.u[0] = pu.x; pa.u[1] = pu.y; pa.u[2] = pu.z; pa.u[3] = pu.w;
      #pragma unroll
      for (int dt = 0; dt < 8; ++dt) {
        int d = dt * 16 + l15;
        const uint32_t* vrow = &Vt2[(d >> 1) * LDV + c * 32 + g * 8];
        uint4 U0 = *(const uint4*)vrow;
        uint4 U1 = *(const uint4*)(vrow + 4);
        FragAB vb;
        vb.u[0] = __builtin_amdgcn_perm(U0.y, U0.x, permsel);
        vb.u[1] = __builtin_amdgcn_perm(U0.w, U0.z, permsel);
        vb.u[2] = __builtin_amdgcn_perm(U1.y, U1.x, permsel);
        vb.u[3] = __builtin_amdgcn_perm(U1.w, U1.z, permsel);
        o[dt] = __builtin_amdgcn_mfma_f32_16x16x32_bf16(pa.v, vb.v, o[dt], 0, 0, 0);
      }
    }
  }

  // ---- epilogue: out = O / (l * 0.8) ----
  float* ob = out + ((size_t)b * 2048 + m0 + wave * 16 + 4 * g) * 128;
  #pragma unroll
  for (int r = 0; r < 4; ++r) {
    float sc = 1.0f / (lsum[r] * 0.8f);
    #pragma unroll
    for (int dt = 0; dt < 8; ++dt)
      ob[r * 128 + dt * 16 + l15] = o[dt][r] * sc;
  }
}

extern "C" void kernel_launch(void* const* d_in, const int* in_sizes, int n_in,
                              void* d_out, int out_size, void* d_ws, size_t ws_size,
                              hipStream_t stream) {
  const float* x1 = (const float*)d_in[0];
  const float* x2 = (const float*)d_in[1];
  float* out = (float*)d_out;
  dim3 grid(32, 8, 1);   // (m-tile, batch)
  dim3 block(256, 1, 1); // 4 waves; each wave owns 16 Q rows
  attn_kernel<<<grid, block, 0, stream>>>(x1, x2, out);
}

// Round 2
// 177.217 us; speedup vs baseline: 1.4708x; 1.4708x over previous
//
#include <hip/hip_runtime.h>
#include <stdint.h>

// ---------------------------------------------------------------------------
// Fused attention: out = dropout(softmax(0.5 * x1 @ x2^T), p=0.2, jax key 42) @ x2
// B=8, M=N=2048, D=128, fp32 in/out. bf16 MFMA (16x16x32), flash-style online
// softmax, bitwise-exact JAX threefry dropout mask (partitionable scheme).
//
// R2: occupancy fix. M-tile 32, in-block N-split: wave pair {0,1} handles
// n in [0,1024), pair {2,3} handles [1024,2048), each with its own Kt/Vt2 LDS
// copy. Grid (64,8) = 512 blocks -> 2 blocks/CU -> 8 waves/CU (was 4).
// Flash-decode (m,l,O) merge between partner waves in the epilogue.
// ---------------------------------------------------------------------------

typedef __bf16 bf16x8 __attribute__((ext_vector_type(8)));
typedef float f32x4 __attribute__((ext_vector_type(4)));

union FragAB {
  bf16x8 v;
  uint32_t u[4];
};

__device__ __forceinline__ uint32_t rotl32(uint32_t x, uint32_t r) {
  return (x << r) | (x >> (32u - r));   // -> v_alignbit_b32
}

// JAX threefry2x32 with key (0, 42)
__device__ __forceinline__ void threefry2x32_k42(uint32_t in0, uint32_t in1,
                                                 uint32_t& o0, uint32_t& o1) {
  const uint32_t ks0 = 0u;
  const uint32_t ks1 = 42u;
  const uint32_t ks2 = 0x1BD11BDAu ^ 0u ^ 42u;
  uint32_t x0 = in0 + ks0;
  uint32_t x1 = in1 + ks1;
#define TFR(r) { x0 += x1; x1 = rotl32(x1, r); x1 ^= x0; }
  TFR(13u) TFR(15u) TFR(26u) TFR(6u)
  x0 += ks1; x1 += ks2 + 1u;
  TFR(17u) TFR(29u) TFR(16u) TFR(24u)
  x0 += ks2; x1 += ks0 + 2u;
  TFR(13u) TFR(15u) TFR(26u) TFR(6u)
  x0 += ks0; x1 += ks1 + 3u;
  TFR(17u) TFR(29u) TFR(16u) TFR(24u)
  x0 += ks1; x1 += ks2 + 4u;
  TFR(13u) TFR(15u) TFR(26u) TFR(6u)
  x0 += ks2; x1 += ks0 + 5u;
#undef TFR
  o0 = x0; o1 = x1;
}

__device__ __forceinline__ uint32_t pack_bf16(float a, float b) {
  __bf16 ba = (__bf16)a;   // RTNE
  __bf16 bb = (__bf16)b;
  uint32_t ua = (uint32_t)__builtin_bit_cast(uint16_t, ba);
  uint32_t ub = (uint32_t)__builtin_bit_cast(uint16_t, bb);
  return ua | (ub << 16);
}

// keep iff uniform < 0.8f  <=>  bits < 6710887<<9
#define KEEP_LT 3435974144u

__launch_bounds__(256, 2)
__global__ void attn_kernel(const float* __restrict__ x1,
                            const float* __restrict__ x2,
                            float* __restrict__ out) {
  constexpr int LDK = 136;  // Kt row stride (bf16): 272 B, 16B-aligned, 2-way banks (free)
  constexpr int LDV = 68;   // Vt2 row stride (u32): 272 B, conflict-free b128 reads
  constexpr int LDP = 72;   // Pbuf row stride (bf16): 144 B, 16B-aligned

  // 2 N-halves, each with its own staging copy. Total 78,848 B -> 2 blocks/CU.
  __shared__ __attribute__((aligned(16))) uint16_t Kt[2][64 * LDK];
  __shared__ __attribute__((aligned(16))) uint32_t Vt2[2][64 * LDV];
  __shared__ __attribute__((aligned(16))) uint16_t Pbuf[4][16 * LDP];

  const int tid = threadIdx.x;
  const int wave = tid >> 6;
  const int lane = tid & 63;
  const int l15 = lane & 15;
  const int g = lane >> 4;
  const int half = wave >> 1;   // which N-half this wave works on
  const int slab = wave & 1;    // which 16-row slab of the 32-row M-tile
  const int hid = tid & 127;    // thread id within the half-pair (128 threads)
  const int b = blockIdx.y;
  const int m0 = blockIdx.x * 32;

  // ---- Q fragments, scaled by 0.5*log2(e) so scores are in log2 domain ----
  const float QSCALE = 0.5f * 1.44269504088896340736f;
  const int m_arow = m0 + slab * 16 + l15;       // A-operand row for this lane
  FragAB qf[4];
  const float* qp_base = x1 + ((size_t)b * 2048 + m_arow) * 128;
  #pragma unroll
  for (int c = 0; c < 4; ++c) {
    const float* qp = qp_base + c * 32 + g * 8;
    float4 f0 = *(const float4*)(qp);
    float4 f1 = *(const float4*)(qp + 4);
    qf[c].u[0] = pack_bf16(f0.x * QSCALE, f0.y * QSCALE);
    qf[c].u[1] = pack_bf16(f0.z * QSCALE, f0.w * QSCALE);
    qf[c].u[2] = pack_bf16(f1.x * QSCALE, f1.y * QSCALE);
    qf[c].u[3] = pack_bf16(f1.z * QSCALE, f1.w * QSCALE);
  }

  // softmax state: this lane owns rows m0 + slab*16 + 4*g + r (C/D layout rows)
  float m2[4], lsum[4];
  #pragma unroll
  for (int r = 0; r < 4; ++r) { m2[r] = -INFINITY; lsum[r] = 0.0f; }
  f32x4 o[8];
  #pragma unroll
  for (int dt = 0; dt < 8; ++dt) o[dt] = (f32x4){0.f, 0.f, 0.f, 0.f};

  uint32_t rng_row_base[4];
  #pragma unroll
  for (int r = 0; r < 4; ++r)
    rng_row_base[r] = (uint32_t)b * 4194304u +
                      (uint32_t)(m0 + slab * 16 + 4 * g + r) * 2048u + (uint32_t)l15;

  const float* x2b = x2 + (size_t)b * 2048 * 128;
  uint16_t* KtH = &Kt[half][0];
  uint32_t* VtH = &Vt2[half][0];

  for (int ntl = 0; ntl < 16; ++ntl) {
    const int n0 = half * 1024 + ntl * 64;   // this half's N-tile base
    __syncthreads();  // previous tile's LDS reads complete before overwrite
    // ---- pair stages x2 rows n0..n0+63 into its Kt (row-major) + Vt2 (transposed) ----
    #pragma unroll
    for (int i = 0; i < 16; ++i) {
      int f = i * 128 + hid;      // float4 index in tile (64 rows x 32 quads)
      int n = f >> 5;
      int dq = f & 31;
      float4 v = *((const float4*)x2b + (size_t)(n0 + n) * 32 + dq);
      uint32_t p0 = pack_bf16(v.x, v.y);
      uint32_t p1 = pack_bf16(v.z, v.w);
      *(uint2*)&KtH[n * LDK + dq * 4] = make_uint2(p0, p1);   // 8B aligned
      VtH[(dq * 2 + 0) * LDV + n] = p0;   // d-pair (4dq, 4dq+1) at col n
      VtH[(dq * 2 + 1) * LDV + n] = p1;   // d-pair (4dq+2, 4dq+3)
    }
    __syncthreads();

    // ---- S = Q K^T : 4 tiles of 16 cols, K=128 over 4 chunks ----
    f32x4 s[4];
    #pragma unroll
    for (int t = 0; t < 4; ++t) {
      f32x4 acc = (f32x4){0.f, 0.f, 0.f, 0.f};
      #pragma unroll
      for (int c = 0; c < 4; ++c) {
        FragAB kb;
        uint4 kk = *(const uint4*)&KtH[(t * 16 + l15) * LDK + c * 32 + g * 8];
        kb.u[0] = kk.x; kb.u[1] = kk.y; kb.u[2] = kk.z; kb.u[3] = kk.w;
        acc = __builtin_amdgcn_mfma_f32_16x16x32_bf16(qf[c].v, kb.v, acc, 0, 0, 0);
      }
      s[t] = acc;
    }

    // ---- online softmax (log2 domain) ----
    float tmax[4];
    #pragma unroll
    for (int r = 0; r < 4; ++r)
      tmax[r] = fmaxf(fmaxf(s[0][r], s[1][r]), fmaxf(s[2][r], s[3][r]));
    #pragma unroll
    for (int off = 1; off < 16; off <<= 1) {
      #pragma unroll
      for (int r = 0; r < 4; ++r)
        tmax[r] = fmaxf(tmax[r], __shfl_xor(tmax[r], off));
    }
    float alpha[4];
    #pragma unroll
    for (int r = 0; r < 4; ++r) {
      float mn = fmaxf(m2[r], tmax[r]);
      alpha[r] = __builtin_amdgcn_exp2f(m2[r] - mn);
      m2[r] = mn;
    }
    float pvals[4][4];
    float rsum[4] = {0.f, 0.f, 0.f, 0.f};
    #pragma unroll
    for (int t = 0; t < 4; ++t) {
      #pragma unroll
      for (int r = 0; r < 4; ++r) {
        float p = __builtin_amdgcn_exp2f(s[t][r] - m2[r]);
        pvals[t][r] = p;
        rsum[r] += p;   // denominator uses UNMASKED probs
      }
    }
    #pragma unroll
    for (int off = 1; off < 16; off <<= 1) {
      #pragma unroll
      for (int r = 0; r < 4; ++r)
        rsum[r] += __shfl_xor(rsum[r], off);
    }
    #pragma unroll
    for (int r = 0; r < 4; ++r)
      lsum[r] = lsum[r] * alpha[r] + rsum[r];
    #pragma unroll
    for (int dt = 0; dt < 8; ++dt) {
      #pragma unroll
      for (int r = 0; r < 4; ++r)
        o[dt][r] *= alpha[r];
    }

    // ---- dropout mask (bitwise JAX threefry) + P -> LDS (C/D -> A layout) ----
    uint16_t* pb = &Pbuf[wave][0];
    #pragma unroll
    for (int r = 0; r < 4; ++r) {
      uint32_t ibase = rng_row_base[r] + (uint32_t)n0;
      #pragma unroll
      for (int t = 0; t < 4; ++t) {
        uint32_t idx = ibase + t * 16;
        uint32_t o0, o1;
        threefry2x32_k42(0u, idx, o0, o1);
        uint32_t bits = o0 ^ o1;
        float pm = (bits < KEEP_LT) ? pvals[t][r] : 0.0f;
        __bf16 pmb = (__bf16)pm;
        pb[(4 * g + r) * LDP + t * 16 + l15] = __builtin_bit_cast(uint16_t, pmb);
      }
    }

    // ---- O += P V  (A-frag from Pbuf, B-frag from packed Vt2 via v_perm) ----
    const uint32_t permsel = (l15 & 1) ? 0x07060302u : 0x05040100u;
    #pragma unroll
    for (int c = 0; c < 2; ++c) {
      FragAB pa;
      uint4 pu = *(const uint4*)&pb[l15 * LDP + c * 32 + g * 8];
      pa.u[0] = pu.x; pa.u[1] = pu.y; pa.u[2] = pu.z; pa.u[3] = pu.w;
      #pragma unroll
      for (int dt = 0; dt < 8; ++dt) {
        int d = dt * 16 + l15;
        const uint32_t* vrow = &VtH[(d >> 1) * LDV + c * 32 + g * 8];
        uint4 U0 = *(const uint4*)vrow;
        uint4 U1 = *(const uint4*)(vrow + 4);
        FragAB vb;
        vb.u[0] = __builtin_amdgcn_perm(U0.y, U0.x, permsel);
        vb.u[1] = __builtin_amdgcn_perm(U0.w, U0.z, permsel);
        vb.u[2] = __builtin_amdgcn_perm(U1.y, U1.x, permsel);
        vb.u[3] = __builtin_amdgcn_perm(U1.w, U1.z, permsel);
        o[dt] = __builtin_amdgcn_mfma_f32_16x16x32_bf16(pa.v, vb.v, o[dt], 0, 0, 0);
      }
    }
  }

  // ---- epilogue: flash-decode merge of the two N-halves, then write out ----
  // Reuse Kt as scratch: 40 items/lane (32 O + 4 m + 4 l), interleaved layout
  // comb[item*128 + src_lane] -> stride-1 across lanes, conflict-free.
  __syncthreads();   // all waves done reading Kt/Vt2 for the last tile
  float* comb = (float*)&Kt[0][0];   // 34,816 B available, need 20,480 B
  if (half == 1) {
    const int src = slab * 64 + lane;
    #pragma unroll
    for (int dt = 0; dt < 8; ++dt)
      #pragma unroll
      for (int r = 0; r < 4; ++r)
        comb[(dt * 4 + r) * 128 + src] = o[dt][r];
    #pragma unroll
    for (int r = 0; r < 4; ++r) {
      comb[(32 + r) * 128 + src] = m2[r];
      comb[(36 + r) * 128 + src] = lsum[r];
    }
  }
  __syncthreads();
  if (half == 0) {
    const int src = slab * 64 + lane;
    float mb[4], lb[4];
    #pragma unroll
    for (int r = 0; r < 4; ++r) {
      mb[r] = comb[(32 + r) * 128 + src];
      lb[r] = comb[(36 + r) * 128 + src];
    }
    float aa[4], ab[4], scale[4];
    #pragma unroll
    for (int r = 0; r < 4; ++r) {
      float ms = fmaxf(m2[r], mb[r]);
      aa[r] = __builtin_amdgcn_exp2f(m2[r] - ms);
      ab[r] = __builtin_amdgcn_exp2f(mb[r] - ms);
      float lt = lsum[r] * aa[r] + lb[r] * ab[r];
      scale[r] = 1.0f / (lt * 0.8f);
    }
    float* ob = out + ((size_t)b * 2048 + m0 + slab * 16 + 4 * g) * 128;
    #pragma unroll
    for (int r = 0; r < 4; ++r) {
      #pragma unroll
      for (int dt = 0; dt < 8; ++dt) {
        float ov = comb[(dt * 4 + r) * 128 + src];
        ob[r * 128 + dt * 16 + l15] = (o[dt][r] * aa[r] + ov * ab[r]) * scale[r];
      }
    }
  }
}

extern "C" void kernel_launch(void* const* d_in, const int* in_sizes, int n_in,
                              void* d_out, int out_size, void* d_ws, size_t ws_size,
                              hipStream_t stream) {
  const float* x1 = (const float*)d_in[0];
  const float* x2 = (const float*)d_in[1];
  float* out = (float*)d_out;
  dim3 grid(64, 8, 1);   // (m-tile of 32 rows, batch)
  dim3 block(256, 1, 1); // 4 waves = 2 N-half pairs x 2 row-slabs
  attn_kernel<<<grid, block, 0, stream>>>(x1, x2, out);
}